// Round 9
// baseline (291.278 us; speedup 1.0000x reference)
//
#include <hip/hip_runtime.h>
#include <hip/hip_bf16.h>

#define DM 768
#define NH 12
#define HD 64
#define B_ 4
#define S_ 2048
#define MT (B_*S_)   // 8192 rows

typedef unsigned short u16;
typedef __attribute__((ext_vector_type(8))) short bf16x8;
typedef __attribute__((ext_vector_type(4))) float f32x4;
typedef __attribute__((ext_vector_type(4))) short s16x4;
typedef __attribute__((ext_vector_type(4))) unsigned u32x4;

__device__ __forceinline__ u16 f2bf(float f) {
    union { float f; unsigned u; } x; x.f = f;
    unsigned r = x.u + 0x7fffu + ((x.u >> 16) & 1u);   // RNE
    return (u16)(r >> 16);
}

__device__ __forceinline__ unsigned pk2(float a, float b) {
    union { __hip_bfloat162 h; unsigned u; } cv;
    cv.h = __float22bfloat162_rn(float2{a, b});
    return cv.u;
}

// gfx950 cross-lane half-swaps (both outputs live via "+v","+v"):
__device__ __forceinline__ void swap32(unsigned& a, unsigned& b) {
    asm volatile("v_permlane32_swap_b32 %0, %1" : "+v"(a), "+v"(b));
}
__device__ __forceinline__ void swap16(unsigned& a, unsigned& b) {
    asm volatile("v_permlane16_swap_b32 %0, %1" : "+v"(a), "+v"(b));
}

#define GLD_LDS(gp, lp) \
    __builtin_amdgcn_global_load_lds( \
        (const __attribute__((address_space(1))) void*)(gp), \
        (__attribute__((address_space(3))) void*)(lp), 16, 0, 0)

// ---------------- fp32 -> bf16 conversion, WEIGHTS ONLY (R9) ----------------
// X conversion deleted: qkv_gemm now stages fp32 X directly (cvt on LDS read).
__global__ void cvt_w(const float* __restrict__ w0, const float* __restrict__ w1,
                      const float* __restrict__ w2, const float* __restrict__ w3,
                      u16* __restrict__ d0, u16* __restrict__ d1,
                      u16* __restrict__ d2, u16* __restrict__ d3,
                      int blocksPer) {
    int sel = blockIdx.x / blocksPer;
    int rel = blockIdx.x % blocksPer;
    const float* s = (sel == 0) ? w0 : (sel == 1) ? w1 : (sel == 2) ? w2 : w3;
    u16* d = (sel == 0) ? d0 : (sel == 1) ? d1 : (sel == 2) ? d2 : d3;
    int i = (rel * 256 + threadIdx.x) * 4;
    float4 v = *(const float4*)(s + i);
    s16x4 o;
    o.x = (short)f2bf(v.x); o.y = (short)f2bf(v.y);
    o.z = (short)f2bf(v.z); o.w = (short)f2bf(v.w);
    *(s16x4*)(d + i) = o;
}

// ---------------- shared 128x128-tile MFMA core, bf16 A/B (o_gemm) ----------------
__device__ __forceinline__ void gemm_core_128(
    const u16* __restrict__ A, const u16* __restrict__ B,
    int m0, int n0, u16* As, u16* Bs, f32x4 acc[4][4])
{
    const int tid = threadIdx.x;
    const int lane = tid & 63;
    const int lr = lane & 15, quad = lane >> 4;
    const int wave = tid >> 6;
    const int wm = (wave & 1) * 64, wn = (wave >> 1) * 64;

    for (int ks = 0; ks < 24; ++ks) {
        #pragma unroll
        for (int r = 0; r < 2; ++r) {
            int idx = r * 256 + tid;
            int row = idx >> 2, col = (idx & 3) * 8;
            GLD_LDS(A + (size_t)(m0 + row) * DM + ks * 32 + col, As + idx * 8);
            GLD_LDS(B + (size_t)(n0 + row) * DM + ks * 32 + col, Bs + idx * 8);
        }
        __syncthreads();
        bf16x8 a[4], b[4];
        #pragma unroll
        for (int i = 0; i < 4; ++i) a[i] = *(const bf16x8*)(As + (wm + i * 16 + lr) * 32 + quad * 8);
        #pragma unroll
        for (int j = 0; j < 4; ++j) b[j] = *(const bf16x8*)(Bs + (wn + j * 16 + lr) * 32 + quad * 8);
        #pragma unroll
        for (int i = 0; i < 4; ++i)
            #pragma unroll
            for (int j = 0; j < 4; ++j)
                acc[i][j] = __builtin_amdgcn_mfma_f32_16x16x32_bf16(a[i], b[j], acc[i][j], 0, 0, 0);
        __syncthreads();
    }
}

// ---------------- fused QKV projection GEMM (R9: fp32 X staged directly) ----------------
// A-side: fp32 X tile (128x32 fl = 16KB) staged via 4 gload_lds/thread, XOR-swizzled
// source (rule #21: linear LDS dest + inverse-swizzled global col + swizzled read);
// fragment read = 2x ds_read_b128 fp32 + 4 pk2 (RNE, numerically == old cvt path).
// B-side bf16 unchanged. Deletes the 22us X-conversion pass entirely.
// R6 T1 remap retained: all 6 nt of one X-panel on the same XCD L2.
__global__ __launch_bounds__(256) void qkv_gemm(
    const float* __restrict__ Xq, const float* __restrict__ Xk, const float* __restrict__ Xv,
    const u16* __restrict__ Wq, const u16* __restrict__ Wk, const u16* __restrict__ Wv,
    const float* __restrict__ bQ, const float* __restrict__ bK, const float* __restrict__ bV,
    u16* __restrict__ Qo, u16* __restrict__ Ko, u16* __restrict__ VTo)
{
    __shared__ __align__(16) float Asf[128 * 32];   // 16 KB fp32 A tile
    __shared__ __align__(16) u16 Bs[128 * 32];      //  8 KB bf16 B tile

    const int xcd  = blockIdx.x & 7;
    const int slot = blockIdx.x >> 3;           // 0..143
    const int nt   = slot % 6;
    const int gg   = xcd * 24 + slot / 6;       // global mt-group 0..191
    const int mat  = gg / 64;                   // uniform per block
    const int mt   = gg % 64;
    const float* X = (mat == 0) ? Xq : (mat == 1 ? Xk : Xv);
    const u16* W = (mat == 0) ? Wq : (mat == 1 ? Wk : Wv);
    const float* bias = (mat == 0) ? bQ : (mat == 1 ? bK : bV);

    const int tid = threadIdx.x;
    const int lane = tid & 63;
    const int lr = lane & 15, quad = lane >> 4;
    const int wave = tid >> 6;
    const int wm = (wave & 1) * 64, wn = (wave >> 1) * 64;
    const int m0 = mt * 128 + wm;
    const int n0 = nt * 128 + wn;

    f32x4 acc[4][4] = {};

    for (int ks = 0; ks < 24; ++ks) {
        // A: 1024 chunks of 16B (4 floats); 8 chunks/row; source col XOR-swizzled
        #pragma unroll
        for (int j = 0; j < 4; ++j) {
            int ch  = j * 256 + tid;
            int row = ch >> 3;
            int cl  = (ch & 7) ^ (row & 7);
            GLD_LDS(X + (size_t)(mt * 128 + row) * DM + ks * 32 + cl * 4, Asf + ch * 4);
        }
        // B: 512 chunks of 16B (8 bf16), linear (unchanged)
        #pragma unroll
        for (int r = 0; r < 2; ++r) {
            int idx = r * 256 + tid;
            int row = idx >> 2, col = (idx & 3) * 8;
            GLD_LDS(W + (size_t)(nt * 128 + row) * DM + ks * 32 + col, Bs + idx * 8);
        }
        __syncthreads();

        bf16x8 a[4], b[4];
        #pragma unroll
        for (int i = 0; i < 4; ++i) {
            int row = wm + i * 16 + lr;
            int clo = (2 * quad) ^ (row & 7);
            int chi = (2 * quad + 1) ^ (row & 7);
            f32x4 lo = *(const f32x4*)(Asf + row * 32 + clo * 4);
            f32x4 hi = *(const f32x4*)(Asf + row * 32 + chi * 4);
            u32x4 P = {pk2(lo[0], lo[1]), pk2(lo[2], lo[3]),
                       pk2(hi[0], hi[1]), pk2(hi[2], hi[3])};
            a[i] = __builtin_bit_cast(bf16x8, P);
        }
        #pragma unroll
        for (int j = 0; j < 4; ++j) b[j] = *(const bf16x8*)(Bs + (wn + j * 16 + lr) * 32 + quad * 8);
        #pragma unroll
        for (int i = 0; i < 4; ++i)
            #pragma unroll
            for (int j = 0; j < 4; ++j)
                acc[i][j] = __builtin_amdgcn_mfma_f32_16x16x32_bf16(a[i], b[j], acc[i][j], 0, 0, 0);
        __syncthreads();
    }

    const int bb = m0 / S_, s0 = m0 % S_, h = n0 / HD;
    if (mat < 2) {
        u16* O = (mat == 0) ? Qo : Ko;
        const float qs = (mat == 0) ? 0.18033688011112042f : 1.0f;  // (1/8)*log2(e)
        #pragma unroll
        for (int jj = 0; jj < 4; ++jj) {
            float bv = bias[n0 + jj * 16 + lr];
            #pragma unroll
            for (int i = 0; i < 4; ++i)
                #pragma unroll
                for (int r = 0; r < 4; ++r) {
                    int s = s0 + i * 16 + quad * 4 + r;
                    O[((size_t)(bb * NH + h) * S_ + s) * HD + jj * 16 + lr] = f2bf((acc[i][jj][r] + bv) * qs);
                }
        }
    } else {
        #pragma unroll
        for (int jj = 0; jj < 4; ++jj) {
            float bv = bias[n0 + jj * 16 + lr];
            #pragma unroll
            for (int i = 0; i < 4; ++i) {
                int s = s0 + i * 16 + quad * 4;
                s16x4 o;
                o.x = (short)f2bf(acc[i][jj][0] + bv);
                o.y = (short)f2bf(acc[i][jj][1] + bv);
                o.z = (short)f2bf(acc[i][jj][2] + bv);
                o.w = (short)f2bf(acc[i][jj][3] + bv);
                *(s16x4*)(VTo + ((size_t)(bb * NH + h) * HD + jj * 16 + lr) * S_ + s) = o;
            }
        }
    }
}

// ---------------- flash attention (causal, NO-max softmax) ----------------
// R8/R6 structure (best): block owns 128 q-rows (4 waves x 32); K/V tile staged once
// per block into double-buffered LDS via 16 coalesced global_load_lds; one barrier
// per tile; XOR swizzle both-sides; swapped QK^T + permlane in-register transpose;
// per-wave epilogue.
__global__ __launch_bounds__(256, 3) void attn_kernel(
    const u16* __restrict__ Q, const u16* __restrict__ K,
    const u16* __restrict__ VT, u16* __restrict__ CTX)
{
    const int tid = threadIdx.x;
    const int wave = tid >> 6;
    const int lane = tid & 63;
    const int lr = lane & 15, quad = lane >> 4;

    const int xcd = blockIdx.x & 7;
    const int i2  = blockIdx.x >> 3;            // 0..95
    const int bh  = xcd * 6 + (i2 % 6);
    const int qc  = 15 - (i2 / 6);              // longest q-chunks first
    const int Q0  = qc * 128;
    const int q0w = Q0 + wave * 32;             // this wave's 32 q-rows

    const u16* Qb = Q  + (size_t)bh * S_ * HD;
    const u16* Kb = K  + (size_t)bh * S_ * HD;
    const u16* Vb = VT + (size_t)bh * HD * S_;

    // double-buffered K/V tiles: 64 rows x 64 elems bf16 each = 8KB; total 32KB
    __shared__ __align__(16) u16 kbuf[2][64 * 64];
    __shared__ __align__(16) u16 vbuf[2][64 * 64];

    bf16x8 aq[2][2];
    #pragma unroll
    for (int mi = 0; mi < 2; ++mi)
        #pragma unroll
        for (int kk = 0; kk < 2; ++kk)
            aq[mi][kk] = *(const bf16x8*)(Qb + (size_t)(q0w + mi * 16 + lr) * HD + kk * 32 + quad * 8);

    f32x4 o[2][4] = {};
    f32x4 lacc[2] = {};
    bf16x8 ones;
    #pragma unroll
    for (int j = 0; j < 8; ++j) ones[j] = (short)0x3F80;   // bf16 1.0

    const int KT  = 2 * qc + 1;                 // block-uniform last tile
    const int ktw = (q0w + 31) >> 6;            // this wave's last tile

#define STAGE_KV(b, kk0) do {                                                   \
        _Pragma("unroll")                                                       \
        for (int j = 0; j < 2; ++j) {                                           \
            int ch  = ((j * 4 + wave) << 6) + lane;                             \
            int row = ch >> 3;                                                  \
            int cl  = (ch & 7) ^ (row & 7);                                     \
            GLD_LDS(Kb + (size_t)((kk0) + row) * HD + cl * 8, &kbuf[b][ch * 8]);\
            GLD_LDS(Vb + (size_t)row * S_ + (kk0) + cl * 8, &vbuf[b][ch * 8]);  \
        }                                                                       \
    } while (0)

    STAGE_KV(0, 0);
    __syncthreads();

    for (int kt = 0; kt <= KT; ++kt) {
        const int cur = kt & 1;
        if (kt < KT) STAGE_KV(cur ^ 1, (kt + 1) << 6);   // prefetch next tile

        if (kt <= ktw) {                                  // wave-uniform guard
            const int k0 = kt << 6;

            // K fragments from LDS (swizzled read)
            bf16x8 bk[4][2];
            #pragma unroll
            for (int t = 0; t < 4; ++t)
                #pragma unroll
                for (int kk = 0; kk < 2; ++kk) {
                    int row = t * 16 + lr;
                    int cp  = (kk * 4 + quad) ^ (row & 7);
                    bk[t][kk] = *(const bf16x8*)(&kbuf[cur][row * 64 + cp * 8]);
                }

            // swapped QK^T: lane holds q=lr, key=16t+quad*4+r
            f32x4 sT[2][4];
            #pragma unroll
            for (int mi = 0; mi < 2; ++mi)
                #pragma unroll
                for (int t = 0; t < 4; ++t) {
                    f32x4 z = {0.f, 0.f, 0.f, 0.f};
                    z = __builtin_amdgcn_mfma_f32_16x16x32_bf16(bk[t][0], aq[mi][0], z, 0, 0, 0);
                    z = __builtin_amdgcn_mfma_f32_16x16x32_bf16(bk[t][1], aq[mi][1], z, 0, 0, 0);
                    sT[mi][t] = z;
                }

            if (kt == ktw) {   // diagonal tile: causal mask (exp2(-inf) = 0)
                #pragma unroll
                for (int mi = 0; mi < 2; ++mi) {
                    int qrow = q0w + mi * 16 + lr;
                    #pragma unroll
                    for (int t = 0; t < 4; ++t)
                        #pragma unroll
                        for (int r = 0; r < 4; ++r) {
                            int key = k0 + t * 16 + quad * 4 + r;
                            if (key > qrow) sT[mi][t][r] = -INFINITY;
                        }
                }
            }

            // V fragments from LDS (swizzled read)
            bf16x8 bv[4][2];
            #pragma unroll
            for (int nv = 0; nv < 4; ++nv)
                #pragma unroll
                for (int c2 = 0; c2 < 2; ++c2) {
                    int row = nv * 16 + lr;
                    int cp  = (c2 * 4 + quad) ^ (row & 7);
                    bv[nv][c2] = *(const bf16x8*)(&vbuf[cur][row * 64 + cp * 8]);
                }

            // exp (Q pre-scaled by scale*log2e) + in-register transpose to A-layout
            bf16x8 pa[2][2];
            #pragma unroll
            for (int mi = 0; mi < 2; ++mi) {
                #pragma unroll
                for (int t = 0; t < 4; ++t)
                    #pragma unroll
                    for (int r = 0; r < 4; ++r)
                        sT[mi][t][r] = exp2f(sT[mi][t][r]);

                #pragma unroll
                for (int c = 0; c < 2; ++c) {
                    unsigned u00 = pk2(sT[mi][2 * c + 0][0], sT[mi][2 * c + 0][1]);
                    unsigned u01 = pk2(sT[mi][2 * c + 0][2], sT[mi][2 * c + 0][3]);
                    unsigned u10 = pk2(sT[mi][2 * c + 1][0], sT[mi][2 * c + 1][1]);
                    unsigned u11 = pk2(sT[mi][2 * c + 1][2], sT[mi][2 * c + 1][3]);
                    swap32(u00, u10); swap16(u00, u10);
                    swap32(u01, u11); swap16(u01, u11);
                    u32x4 P = {u00, u01, u10, u11};
                    pa[mi][c] = __builtin_bit_cast(bf16x8, P);
                }
            }

            #pragma unroll
            for (int mi = 0; mi < 2; ++mi) {
                lacc[mi] = __builtin_amdgcn_mfma_f32_16x16x32_bf16(pa[mi][0], ones, lacc[mi], 0, 0, 0);
                lacc[mi] = __builtin_amdgcn_mfma_f32_16x16x32_bf16(pa[mi][1], ones, lacc[mi], 0, 0, 0);
                #pragma unroll
                for (int nv = 0; nv < 4; ++nv) {
                    o[mi][nv] = __builtin_amdgcn_mfma_f32_16x16x32_bf16(pa[mi][0], bv[nv][0], o[mi][nv], 0, 0, 0);
                    o[mi][nv] = __builtin_amdgcn_mfma_f32_16x16x32_bf16(pa[mi][1], bv[nv][1], o[mi][nv], 0, 0, 0);
                }
            }
        }

        __syncthreads();   // staging of kt+1 done; reads of buf[cur] done
    }
#undef STAGE_KV

    // -------- per-wave epilogue (no cross-wave reduction) --------
    const int bb = bh / NH, h = bh % NH;
    #pragma unroll
    for (int mi = 0; mi < 2; ++mi) {
        f32x4 inv;
        #pragma unroll
        for (int r = 0; r < 4; ++r) inv[r] = 1.0f / lacc[mi][r];
        #pragma unroll
        for (int nv = 0; nv < 4; ++nv)
            #pragma unroll
            for (int r = 0; r < 4; ++r)
                CTX[(size_t)(bb * S_ + q0w + mi * 16 + quad * 4 + r) * DM + h * HD + nv * 16 + lr]
                    = f2bf(o[mi][nv][r] * inv[r]);
    }
}

// ---------------- output projection GEMM (LDS-staged, fp32 out) ----------------
// R6 (T1): XCD-aware bijective remap. 384 = 8 XCD x 8 mt x 6 nt.
__global__ __launch_bounds__(256) void o_gemm(
    const u16* __restrict__ X, const u16* __restrict__ W,
    const float* __restrict__ bias, float* __restrict__ Out)
{
    __shared__ __align__(16) u16 As[128 * 32];
    __shared__ __align__(16) u16 Bs[128 * 32];

    const int xcd  = blockIdx.x & 7;
    const int slot = blockIdx.x >> 3;           // 0..47
    const int nt   = slot % 6;
    const int mt   = xcd * 8 + slot / 6;        // 0..63
    const int lane = threadIdx.x & 63;
    const int lr = lane & 15, quad = lane >> 4;
    const int wave = threadIdx.x >> 6;
    const int m0 = mt * 128 + (wave & 1) * 64;
    const int n0 = nt * 128 + (wave >> 1) * 64;

    f32x4 acc[4][4] = {};
    gemm_core_128(X, W, mt * 128, nt * 128, As, Bs, acc);

    #pragma unroll
    for (int jj = 0; jj < 4; ++jj) {
        float bv = bias[n0 + jj * 16 + lr];
        #pragma unroll
        for (int i = 0; i < 4; ++i)
            #pragma unroll
            for (int r = 0; r < 4; ++r)
                Out[(size_t)(m0 + i * 16 + quad * 4 + r) * DM + n0 + jj * 16 + lr] = acc[i][jj][r] + bv;
    }
}

extern "C" void kernel_launch(void* const* d_in, const int* in_sizes, int n_in,
                              void* d_out, int out_size, void* d_ws, size_t ws_size,
                              hipStream_t stream) {
    const float* q  = (const float*)d_in[0];
    const float* k  = (const float*)d_in[1];
    const float* v  = (const float*)d_in[2];
    const float* WQ = (const float*)d_in[3];
    const float* bQ = (const float*)d_in[4];
    const float* WK = (const float*)d_in[5];
    const float* bK = (const float*)d_in[6];
    const float* WV = (const float*)d_in[7];
    const float* bV = (const float*)d_in[8];
    const float* WO = (const float*)d_in[9];
    const float* bO = (const float*)d_in[10];

    char* ws = (char*)d_ws;
    const size_t SZ_X = (size_t)MT * DM * 2;   // 12,582,912 B
    const size_t SZ_W = (size_t)DM * DM * 2;   //  1,179,648 B
    u16* CTX = (u16*)(ws);
    u16* Wq  = (u16*)(ws + SZ_X);
    u16* Wk  = (u16*)(ws + SZ_X + SZ_W);
    u16* Wv  = (u16*)(ws + SZ_X + 2 * SZ_W);
    u16* Wo  = (u16*)(ws + SZ_X + 3 * SZ_W);
    u16* Qh  = (u16*)(ws + SZ_X + 4 * SZ_W);
    u16* Kh  = (u16*)(ws + 2 * SZ_X + 4 * SZ_W);
    u16* VTh = (u16*)(ws + 3 * SZ_X + 4 * SZ_W);

    const int nW = DM * DM;    // 589,824
    const int wB = nW / 1024;  // 576
    cvt_w<<<4 * wB, 256, 0, stream>>>(WQ, WK, WV, WO, Wq, Wk, Wv, Wo, wB);

    qkv_gemm<<<1152, 256, 0, stream>>>(q, k, v, Wq, Wk, Wv, bQ, bK, bV, Qh, Kh, VTh);
    attn_kernel<<<768, 256, 0, stream>>>(Qh, Kh, VTh, CTX);
    o_gemm<<<384, 256, 0, stream>>>(CTX, Wo, bO, (float*)d_out);
}

// Round 10
// 276.703 us; speedup vs baseline: 1.0527x; 1.0527x over previous
//
#include <hip/hip_runtime.h>
#include <hip/hip_bf16.h>

#define DM 768
#define NH 12
#define HD 64
#define B_ 4
#define S_ 2048
#define MT (B_*S_)   // 8192 rows

typedef unsigned short u16;
typedef __attribute__((ext_vector_type(8))) short bf16x8;
typedef __attribute__((ext_vector_type(4))) float f32x4;
typedef __attribute__((ext_vector_type(4))) short s16x4;
typedef __attribute__((ext_vector_type(4))) unsigned u32x4;

__device__ __forceinline__ u16 f2bf(float f) {
    union { float f; unsigned u; } x; x.f = f;
    unsigned r = x.u + 0x7fffu + ((x.u >> 16) & 1u);   // RNE
    return (u16)(r >> 16);
}

__device__ __forceinline__ unsigned pk2(float a, float b) {
    union { __hip_bfloat162 h; unsigned u; } cv;
    cv.h = __float22bfloat162_rn(float2{a, b});
    return cv.u;
}

// gfx950 cross-lane half-swaps (both outputs live via "+v","+v"):
__device__ __forceinline__ void swap32(unsigned& a, unsigned& b) {
    asm volatile("v_permlane32_swap_b32 %0, %1" : "+v"(a), "+v"(b));
}
__device__ __forceinline__ void swap16(unsigned& a, unsigned& b) {
    asm volatile("v_permlane16_swap_b32 %0, %1" : "+v"(a), "+v"(b));
}

#define GLD_LDS(gp, lp) \
    __builtin_amdgcn_global_load_lds( \
        (const __attribute__((address_space(1))) void*)(gp), \
        (__attribute__((address_space(3))) void*)(lp), 16, 0, 0)

// ---------------- single fused fp32 -> bf16 conversion kernel (R8) ----------------
__global__ void cvt_all(const float* __restrict__ x0, const float* __restrict__ x1,
                        const float* __restrict__ x2,
                        const float* __restrict__ w0, const float* __restrict__ w1,
                        const float* __restrict__ w2, const float* __restrict__ w3,
                        u16* __restrict__ dx0, u16* __restrict__ dx1, u16* __restrict__ dx2,
                        u16* __restrict__ dw0, u16* __restrict__ dw1,
                        u16* __restrict__ dw2, u16* __restrict__ dw3,
                        int xBlocks, int wBlocks) {
    const float* s;
    u16* d;
    int rel;
    if ((int)blockIdx.x < 3 * xBlocks) {
        int sel = blockIdx.x / xBlocks;
        rel = blockIdx.x % xBlocks;
        s = (sel == 0) ? x0 : (sel == 1) ? x1 : x2;
        d = (sel == 0) ? dx0 : (sel == 1) ? dx1 : dx2;
    } else {
        int wb = blockIdx.x - 3 * xBlocks;
        int sel = wb / wBlocks;
        rel = wb % wBlocks;
        s = (sel == 0) ? w0 : (sel == 1) ? w1 : (sel == 2) ? w2 : w3;
        d = (sel == 0) ? dw0 : (sel == 1) ? dw1 : (sel == 2) ? dw2 : dw3;
    }
    int i = (rel * 256 + threadIdx.x) * 4;
    float4 v = *(const float4*)(s + i);
    s16x4 o;
    o.x = (short)f2bf(v.x); o.y = (short)f2bf(v.y);
    o.z = (short)f2bf(v.z); o.w = (short)f2bf(v.w);
    *(s16x4*)(d + i) = o;
}

// ---------------- shared 128x128-tile MFMA core ----------------
// R10: 2-phase double-buffered (attn_kernel's proven loop): prologue-stage tile 0;
// per iter STAGE(next) -> ds_read/MFMA(cur) -> ONE barrier. Staging latency hides
// under 16 MFMAs; barrier count halves vs the R8 single-buffer (48 -> 24).
// As/Bs are [2][128*32] u16 (32 KB total).
__device__ __forceinline__ void gemm_core_128(
    const u16* __restrict__ A, const u16* __restrict__ B,
    int m0, int n0, u16* As, u16* Bs, f32x4 acc[4][4])
{
    const int tid = threadIdx.x;
    const int lane = tid & 63;
    const int lr = lane & 15, quad = lane >> 4;
    const int wave = tid >> 6;
    const int wm = (wave & 1) * 64, wn = (wave >> 1) * 64;

#define STAGE_AB(b, ks) do {                                                      \
        _Pragma("unroll")                                                         \
        for (int r = 0; r < 2; ++r) {                                             \
            int idx = r * 256 + tid;                                              \
            int row = idx >> 2, col = (idx & 3) * 8;                              \
            GLD_LDS(A + (size_t)(m0 + row) * DM + (ks) * 32 + col,                \
                    As + (b) * 4096 + idx * 8);                                   \
            GLD_LDS(B + (size_t)(n0 + row) * DM + (ks) * 32 + col,                \
                    Bs + (b) * 4096 + idx * 8);                                   \
        }                                                                         \
    } while (0)

    STAGE_AB(0, 0);
    __syncthreads();

    for (int ks = 0; ks < 24; ++ks) {
        const int cur = ks & 1;
        if (ks < 23) STAGE_AB(cur ^ 1, ks + 1);   // prefetch next K-tile

        bf16x8 a[4], b[4];
        #pragma unroll
        for (int i = 0; i < 4; ++i)
            a[i] = *(const bf16x8*)(As + cur * 4096 + (wm + i * 16 + lr) * 32 + quad * 8);
        #pragma unroll
        for (int j = 0; j < 4; ++j)
            b[j] = *(const bf16x8*)(Bs + cur * 4096 + (wn + j * 16 + lr) * 32 + quad * 8);
        #pragma unroll
        for (int i = 0; i < 4; ++i)
            #pragma unroll
            for (int j = 0; j < 4; ++j)
                acc[i][j] = __builtin_amdgcn_mfma_f32_16x16x32_bf16(a[i], b[j], acc[i][j], 0, 0, 0);

        __syncthreads();   // staging of ks+1 complete; reads of buf[cur] complete
    }
#undef STAGE_AB
}

// ---------------- fused QKV projection GEMM (LDS-staged, R8 + 2-phase core) ----------------
// R6 (T1): XCD-aware bijective remap: all 6 nt of one X-panel on the same XCD L2.
__global__ __launch_bounds__(256) void qkv_gemm(
    const u16* __restrict__ Xq, const u16* __restrict__ Xk, const u16* __restrict__ Xv,
    const u16* __restrict__ Wq, const u16* __restrict__ Wk, const u16* __restrict__ Wv,
    const float* __restrict__ bQ, const float* __restrict__ bK, const float* __restrict__ bV,
    u16* __restrict__ Qo, u16* __restrict__ Ko, u16* __restrict__ VTo)
{
    __shared__ __align__(16) u16 As[2 * 128 * 32];
    __shared__ __align__(16) u16 Bs[2 * 128 * 32];

    const int xcd  = blockIdx.x & 7;
    const int slot = blockIdx.x >> 3;           // 0..143
    const int nt   = slot % 6;
    const int gg   = xcd * 24 + slot / 6;       // global mt-group 0..191
    const int mat  = gg / 64;                   // uniform per block
    const int mt   = gg % 64;
    const u16* X = (mat == 0) ? Xq : (mat == 1 ? Xk : Xv);
    const u16* W = (mat == 0) ? Wq : (mat == 1 ? Wk : Wv);
    const float* bias = (mat == 0) ? bQ : (mat == 1 ? bK : bV);

    const int lane = threadIdx.x & 63;
    const int lr = lane & 15, quad = lane >> 4;
    const int wave = threadIdx.x >> 6;
    const int m0 = mt * 128 + (wave & 1) * 64;
    const int n0 = nt * 128 + (wave >> 1) * 64;

    f32x4 acc[4][4] = {};
    gemm_core_128(X, W, mt * 128, nt * 128, As, Bs, acc);

    const int bb = m0 / S_, s0 = m0 % S_, h = n0 / HD;
    if (mat < 2) {
        u16* O = (mat == 0) ? Qo : Ko;
        const float qs = (mat == 0) ? 0.18033688011112042f : 1.0f;  // (1/8)*log2(e)
        #pragma unroll
        for (int jj = 0; jj < 4; ++jj) {
            float bv = bias[n0 + jj * 16 + lr];
            #pragma unroll
            for (int i = 0; i < 4; ++i)
                #pragma unroll
                for (int r = 0; r < 4; ++r) {
                    int s = s0 + i * 16 + quad * 4 + r;
                    O[((size_t)(bb * NH + h) * S_ + s) * HD + jj * 16 + lr] = f2bf((acc[i][jj][r] + bv) * qs);
                }
        }
    } else {
        #pragma unroll
        for (int jj = 0; jj < 4; ++jj) {
            float bv = bias[n0 + jj * 16 + lr];
            #pragma unroll
            for (int i = 0; i < 4; ++i) {
                int s = s0 + i * 16 + quad * 4;
                s16x4 o;
                o.x = (short)f2bf(acc[i][jj][0] + bv);
                o.y = (short)f2bf(acc[i][jj][1] + bv);
                o.z = (short)f2bf(acc[i][jj][2] + bv);
                o.w = (short)f2bf(acc[i][jj][3] + bv);
                *(s16x4*)(VTo + ((size_t)(bb * NH + h) * HD + jj * 16 + lr) * S_ + s) = o;
            }
        }
    }
}

// ---------------- flash attention (causal, NO-max softmax) ----------------
// R8/R6 structure (best): block owns 128 q-rows (4 waves x 32); K/V tile staged once
// per block into double-buffered LDS via 16 coalesced global_load_lds; one barrier
// per tile; XOR swizzle both-sides; swapped QK^T + permlane in-register transpose;
// per-wave epilogue.
__global__ __launch_bounds__(256, 3) void attn_kernel(
    const u16* __restrict__ Q, const u16* __restrict__ K,
    const u16* __restrict__ VT, u16* __restrict__ CTX)
{
    const int tid = threadIdx.x;
    const int wave = tid >> 6;
    const int lane = tid & 63;
    const int lr = lane & 15, quad = lane >> 4;

    const int xcd = blockIdx.x & 7;
    const int i2  = blockIdx.x >> 3;            // 0..95
    const int bh  = xcd * 6 + (i2 % 6);
    const int qc  = 15 - (i2 / 6);              // longest q-chunks first
    const int Q0  = qc * 128;
    const int q0w = Q0 + wave * 32;             // this wave's 32 q-rows

    const u16* Qb = Q  + (size_t)bh * S_ * HD;
    const u16* Kb = K  + (size_t)bh * S_ * HD;
    const u16* Vb = VT + (size_t)bh * HD * S_;

    // double-buffered K/V tiles: 64 rows x 64 elems bf16 each = 8KB; total 32KB
    __shared__ __align__(16) u16 kbuf[2][64 * 64];
    __shared__ __align__(16) u16 vbuf[2][64 * 64];

    bf16x8 aq[2][2];
    #pragma unroll
    for (int mi = 0; mi < 2; ++mi)
        #pragma unroll
        for (int kk = 0; kk < 2; ++kk)
            aq[mi][kk] = *(const bf16x8*)(Qb + (size_t)(q0w + mi * 16 + lr) * HD + kk * 32 + quad * 8);

    f32x4 o[2][4] = {};
    f32x4 lacc[2] = {};
    bf16x8 ones;
    #pragma unroll
    for (int j = 0; j < 8; ++j) ones[j] = (short)0x3F80;   // bf16 1.0

    const int KT  = 2 * qc + 1;                 // block-uniform last tile
    const int ktw = (q0w + 31) >> 6;            // this wave's last tile

#define STAGE_KV(b, kk0) do {                                                   \
        _Pragma("unroll")                                                       \
        for (int j = 0; j < 2; ++j) {                                           \
            int ch  = ((j * 4 + wave) << 6) + lane;                             \
            int row = ch >> 3;                                                  \
            int cl  = (ch & 7) ^ (row & 7);                                     \
            GLD_LDS(Kb + (size_t)((kk0) + row) * HD + cl * 8, &kbuf[b][ch * 8]);\
            GLD_LDS(Vb + (size_t)row * S_ + (kk0) + cl * 8, &vbuf[b][ch * 8]);  \
        }                                                                       \
    } while (0)

    STAGE_KV(0, 0);
    __syncthreads();

    for (int kt = 0; kt <= KT; ++kt) {
        const int cur = kt & 1;
        if (kt < KT) STAGE_KV(cur ^ 1, (kt + 1) << 6);   // prefetch next tile

        if (kt <= ktw) {                                  // wave-uniform guard
            const int k0 = kt << 6;

            // K fragments from LDS (swizzled read)
            bf16x8 bk[4][2];
            #pragma unroll
            for (int t = 0; t < 4; ++t)
                #pragma unroll
                for (int kk = 0; kk < 2; ++kk) {
                    int row = t * 16 + lr;
                    int cp  = (kk * 4 + quad) ^ (row & 7);
                    bk[t][kk] = *(const bf16x8*)(&kbuf[cur][row * 64 + cp * 8]);
                }

            // swapped QK^T: lane holds q=lr, key=16t+quad*4+r
            f32x4 sT[2][4];
            #pragma unroll
            for (int mi = 0; mi < 2; ++mi)
                #pragma unroll
                for (int t = 0; t < 4; ++t) {
                    f32x4 z = {0.f, 0.f, 0.f, 0.f};
                    z = __builtin_amdgcn_mfma_f32_16x16x32_bf16(bk[t][0], aq[mi][0], z, 0, 0, 0);
                    z = __builtin_amdgcn_mfma_f32_16x16x32_bf16(bk[t][1], aq[mi][1], z, 0, 0, 0);
                    sT[mi][t] = z;
                }

            if (kt == ktw) {   // diagonal tile: causal mask (exp2(-inf) = 0)
                #pragma unroll
                for (int mi = 0; mi < 2; ++mi) {
                    int qrow = q0w + mi * 16 + lr;
                    #pragma unroll
                    for (int t = 0; t < 4; ++t)
                        #pragma unroll
                        for (int r = 0; r < 4; ++r) {
                            int key = k0 + t * 16 + quad * 4 + r;
                            if (key > qrow) sT[mi][t][r] = -INFINITY;
                        }
                }
            }

            // V fragments from LDS (swizzled read)
            bf16x8 bv[4][2];
            #pragma unroll
            for (int nv = 0; nv < 4; ++nv)
                #pragma unroll
                for (int c2 = 0; c2 < 2; ++c2) {
                    int row = nv * 16 + lr;
                    int cp  = (c2 * 4 + quad) ^ (row & 7);
                    bv[nv][c2] = *(const bf16x8*)(&vbuf[cur][row * 64 + cp * 8]);
                }

            // exp (Q pre-scaled by scale*log2e) + in-register transpose to A-layout
            bf16x8 pa[2][2];
            #pragma unroll
            for (int mi = 0; mi < 2; ++mi) {
                #pragma unroll
                for (int t = 0; t < 4; ++t)
                    #pragma unroll
                    for (int r = 0; r < 4; ++r)
                        sT[mi][t][r] = exp2f(sT[mi][t][r]);

                #pragma unroll
                for (int c = 0; c < 2; ++c) {
                    unsigned u00 = pk2(sT[mi][2 * c + 0][0], sT[mi][2 * c + 0][1]);
                    unsigned u01 = pk2(sT[mi][2 * c + 0][2], sT[mi][2 * c + 0][3]);
                    unsigned u10 = pk2(sT[mi][2 * c + 1][0], sT[mi][2 * c + 1][1]);
                    unsigned u11 = pk2(sT[mi][2 * c + 1][2], sT[mi][2 * c + 1][3]);
                    swap32(u00, u10); swap16(u00, u10);
                    swap32(u01, u11); swap16(u01, u11);
                    u32x4 P = {u00, u01, u10, u11};
                    pa[mi][c] = __builtin_bit_cast(bf16x8, P);
                }
            }

            #pragma unroll
            for (int mi = 0; mi < 2; ++mi) {
                lacc[mi] = __builtin_amdgcn_mfma_f32_16x16x32_bf16(pa[mi][0], ones, lacc[mi], 0, 0, 0);
                lacc[mi] = __builtin_amdgcn_mfma_f32_16x16x32_bf16(pa[mi][1], ones, lacc[mi], 0, 0, 0);
                #pragma unroll
                for (int nv = 0; nv < 4; ++nv) {
                    o[mi][nv] = __builtin_amdgcn_mfma_f32_16x16x32_bf16(pa[mi][0], bv[nv][0], o[mi][nv], 0, 0, 0);
                    o[mi][nv] = __builtin_amdgcn_mfma_f32_16x16x32_bf16(pa[mi][1], bv[nv][1], o[mi][nv], 0, 0, 0);
                }
            }
        }

        __syncthreads();   // staging of kt+1 done; reads of buf[cur] done
    }
#undef STAGE_KV

    // -------- per-wave epilogue (no cross-wave reduction) --------
    const int bb = bh / NH, h = bh % NH;
    #pragma unroll
    for (int mi = 0; mi < 2; ++mi) {
        f32x4 inv;
        #pragma unroll
        for (int r = 0; r < 4; ++r) inv[r] = 1.0f / lacc[mi][r];
        #pragma unroll
        for (int nv = 0; nv < 4; ++nv)
            #pragma unroll
            for (int r = 0; r < 4; ++r)
                CTX[(size_t)(bb * S_ + q0w + mi * 16 + quad * 4 + r) * DM + h * HD + nv * 16 + lr]
                    = f2bf(o[mi][nv][r] * inv[r]);
    }
}

// ---------------- output projection GEMM (LDS-staged, fp32 out) ----------------
// R6 (T1): XCD-aware bijective remap. 384 = 8 XCD x 8 mt x 6 nt.
__global__ __launch_bounds__(256) void o_gemm(
    const u16* __restrict__ X, const u16* __restrict__ W,
    const float* __restrict__ bias, float* __restrict__ Out)
{
    __shared__ __align__(16) u16 As[2 * 128 * 32];
    __shared__ __align__(16) u16 Bs[2 * 128 * 32];

    const int xcd  = blockIdx.x & 7;
    const int slot = blockIdx.x >> 3;           // 0..47
    const int nt   = slot % 6;
    const int mt   = xcd * 8 + slot / 6;        // 0..63
    const int lane = threadIdx.x & 63;
    const int lr = lane & 15, quad = lane >> 4;
    const int wave = threadIdx.x >> 6;
    const int m0 = mt * 128 + (wave & 1) * 64;
    const int n0 = nt * 128 + (wave >> 1) * 64;

    f32x4 acc[4][4] = {};
    gemm_core_128(X, W, mt * 128, nt * 128, As, Bs, acc);

    #pragma unroll
    for (int jj = 0; jj < 4; ++jj) {
        float bv = bias[n0 + jj * 16 + lr];
        #pragma unroll
        for (int i = 0; i < 4; ++i)
            #pragma unroll
            for (int r = 0; r < 4; ++r)
                Out[(size_t)(m0 + i * 16 + quad * 4 + r) * DM + n0 + jj * 16 + lr] = acc[i][jj][r] + bv;
    }
}

extern "C" void kernel_launch(void* const* d_in, const int* in_sizes, int n_in,
                              void* d_out, int out_size, void* d_ws, size_t ws_size,
                              hipStream_t stream) {
    const float* q  = (const float*)d_in[0];
    const float* k  = (const float*)d_in[1];
    const float* v  = (const float*)d_in[2];
    const float* WQ = (const float*)d_in[3];
    const float* bQ = (const float*)d_in[4];
    const float* WK = (const float*)d_in[5];
    const float* bK = (const float*)d_in[6];
    const float* WV = (const float*)d_in[7];
    const float* bV = (const float*)d_in[8];
    const float* WO = (const float*)d_in[9];
    const float* bO = (const float*)d_in[10];

    char* ws = (char*)d_ws;
    const size_t SZ_X = (size_t)MT * DM * 2;   // 12,582,912 B
    const size_t SZ_W = (size_t)DM * DM * 2;   //  1,179,648 B
    u16* Xq = (u16*)(ws);
    u16* Xk = (u16*)(ws + SZ_X);
    u16* Xv = (u16*)(ws + 2 * SZ_X);
    u16* Wq = (u16*)(ws + 3 * SZ_X);
    u16* Wk = (u16*)(ws + 3 * SZ_X + SZ_W);
    u16* Wv = (u16*)(ws + 3 * SZ_X + 2 * SZ_W);
    u16* Wo = (u16*)(ws + 3 * SZ_X + 3 * SZ_W);
    u16* Qh  = (u16*)(ws + 3 * SZ_X + 4 * SZ_W);
    u16* Kh  = (u16*)(ws + 4 * SZ_X + 4 * SZ_W);
    u16* VTh = (u16*)(ws + 5 * SZ_X + 4 * SZ_W);
    u16* CTX = Xq;   // Xq dead after qkv_gemm; reuse

    const int nX = MT * DM;    // 6,291,456
    const int nW = DM * DM;    //   589,824
    const int xB = nX / 1024;  // 6144
    const int wB = nW / 1024;  //  576
    cvt_all<<<3 * xB + 4 * wB, 256, 0, stream>>>(q, k, v, WQ, WK, WV, WO,
                                                 Xq, Xk, Xv, Wq, Wk, Wv, Wo, xB, wB);

    qkv_gemm<<<1152, 256, 0, stream>>>(Xq, Xk, Xv, Wq, Wk, Wv, bQ, bK, bV, Qh, Kh, VTh);
    attn_kernel<<<768, 256, 0, stream>>>(Qh, Kh, VTh, CTX);
    o_gemm<<<384, 256, 0, stream>>>(CTX, Wo, bO, (float*)d_out);
}

// Round 11
// 269.531 us; speedup vs baseline: 1.0807x; 1.0266x over previous
//
#include <hip/hip_runtime.h>
#include <hip/hip_bf16.h>

#define DM 768
#define NH 12
#define HD 64
#define B_ 4
#define S_ 2048
#define MT (B_*S_)   // 8192 rows

typedef unsigned short u16;
typedef __attribute__((ext_vector_type(8))) short bf16x8;
typedef __attribute__((ext_vector_type(4))) float f32x4;
typedef __attribute__((ext_vector_type(4))) short s16x4;
typedef __attribute__((ext_vector_type(4))) unsigned u32x4;

__device__ __forceinline__ u16 f2bf(float f) {
    union { float f; unsigned u; } x; x.f = f;
    unsigned r = x.u + 0x7fffu + ((x.u >> 16) & 1u);   // RNE
    return (u16)(r >> 16);
}

__device__ __forceinline__ unsigned pk2(float a, float b) {
    union { __hip_bfloat162 h; unsigned u; } cv;
    cv.h = __float22bfloat162_rn(float2{a, b});
    return cv.u;
}

// gfx950 cross-lane half-swaps (both outputs live via "+v","+v"):
__device__ __forceinline__ void swap32(unsigned& a, unsigned& b) {
    asm volatile("v_permlane32_swap_b32 %0, %1" : "+v"(a), "+v"(b));
}
__device__ __forceinline__ void swap16(unsigned& a, unsigned& b) {
    asm volatile("v_permlane16_swap_b32 %0, %1" : "+v"(a), "+v"(b));
}

#define GLD_LDS(gp, lp) \
    __builtin_amdgcn_global_load_lds( \
        (const __attribute__((address_space(1))) void*)(gp), \
        (__attribute__((address_space(3))) void*)(lp), 16, 0, 0)

// ---------------- single fused fp32 -> bf16 conversion kernel (R8) ----------------
__global__ void cvt_all(const float* __restrict__ x0, const float* __restrict__ x1,
                        const float* __restrict__ x2,
                        const float* __restrict__ w0, const float* __restrict__ w1,
                        const float* __restrict__ w2, const float* __restrict__ w3,
                        u16* __restrict__ dx0, u16* __restrict__ dx1, u16* __restrict__ dx2,
                        u16* __restrict__ dw0, u16* __restrict__ dw1,
                        u16* __restrict__ dw2, u16* __restrict__ dw3,
                        int xBlocks, int wBlocks) {
    const float* s;
    u16* d;
    int rel;
    if ((int)blockIdx.x < 3 * xBlocks) {
        int sel = blockIdx.x / xBlocks;
        rel = blockIdx.x % xBlocks;
        s = (sel == 0) ? x0 : (sel == 1) ? x1 : x2;
        d = (sel == 0) ? dx0 : (sel == 1) ? dx1 : dx2;
    } else {
        int wb = blockIdx.x - 3 * xBlocks;
        int sel = wb / wBlocks;
        rel = wb % wBlocks;
        s = (sel == 0) ? w0 : (sel == 1) ? w1 : (sel == 2) ? w2 : w3;
        d = (sel == 0) ? dw0 : (sel == 1) ? dw1 : (sel == 2) ? dw2 : dw3;
    }
    int i = (rel * 256 + threadIdx.x) * 4;
    float4 v = *(const float4*)(s + i);
    s16x4 o;
    o.x = (short)f2bf(v.x); o.y = (short)f2bf(v.y);
    o.z = (short)f2bf(v.z); o.w = (short)f2bf(v.w);
    *(s16x4*)(d + i) = o;
}

// ---------------- shared 128x128-tile MFMA core (R8 single-buffer, m97 structure) ----------------
// R10's 2-phase dbuf regressed (58 -> 71us: drain exposed ~300cy after issue); reverted.
__device__ __forceinline__ void gemm_core_128(
    const u16* __restrict__ A, const u16* __restrict__ B,
    int m0, int n0, u16* As, u16* Bs, f32x4 acc[4][4])
{
    const int tid = threadIdx.x;
    const int lane = tid & 63;
    const int lr = lane & 15, quad = lane >> 4;
    const int wave = tid >> 6;
    const int wm = (wave & 1) * 64, wn = (wave >> 1) * 64;

    for (int ks = 0; ks < 24; ++ks) {
        #pragma unroll
        for (int r = 0; r < 2; ++r) {
            int idx = r * 256 + tid;
            int row = idx >> 2, col = (idx & 3) * 8;
            GLD_LDS(A + (size_t)(m0 + row) * DM + ks * 32 + col, As + idx * 8);
            GLD_LDS(B + (size_t)(n0 + row) * DM + ks * 32 + col, Bs + idx * 8);
        }
        __syncthreads();
        bf16x8 a[4], b[4];
        #pragma unroll
        for (int i = 0; i < 4; ++i) a[i] = *(const bf16x8*)(As + (wm + i * 16 + lr) * 32 + quad * 8);
        #pragma unroll
        for (int j = 0; j < 4; ++j) b[j] = *(const bf16x8*)(Bs + (wn + j * 16 + lr) * 32 + quad * 8);
        #pragma unroll
        for (int i = 0; i < 4; ++i)
            #pragma unroll
            for (int j = 0; j < 4; ++j)
                acc[i][j] = __builtin_amdgcn_mfma_f32_16x16x32_bf16(a[i], b[j], acc[i][j], 0, 0, 0);
        __syncthreads();
    }
}

// ---------------- fused QKV projection GEMM (LDS-staged, R8) ----------------
// R6 (T1): XCD-aware bijective remap: all 6 nt of one X-panel on the same XCD L2.
__global__ __launch_bounds__(256) void qkv_gemm(
    const u16* __restrict__ Xq, const u16* __restrict__ Xk, const u16* __restrict__ Xv,
    const u16* __restrict__ Wq, const u16* __restrict__ Wk, const u16* __restrict__ Wv,
    const float* __restrict__ bQ, const float* __restrict__ bK, const float* __restrict__ bV,
    u16* __restrict__ Qo, u16* __restrict__ Ko, u16* __restrict__ VTo)
{
    __shared__ __align__(16) u16 As[128 * 32];
    __shared__ __align__(16) u16 Bs[128 * 32];

    const int xcd  = blockIdx.x & 7;
    const int slot = blockIdx.x >> 3;           // 0..143
    const int nt   = slot % 6;
    const int gg   = xcd * 24 + slot / 6;       // global mt-group 0..191
    const int mat  = gg / 64;                   // uniform per block
    const int mt   = gg % 64;
    const u16* X = (mat == 0) ? Xq : (mat == 1 ? Xk : Xv);
    const u16* W = (mat == 0) ? Wq : (mat == 1 ? Wk : Wv);
    const float* bias = (mat == 0) ? bQ : (mat == 1 ? bK : bV);

    const int lane = threadIdx.x & 63;
    const int lr = lane & 15, quad = lane >> 4;
    const int wave = threadIdx.x >> 6;
    const int m0 = mt * 128 + (wave & 1) * 64;
    const int n0 = nt * 128 + (wave >> 1) * 64;

    f32x4 acc[4][4] = {};
    gemm_core_128(X, W, mt * 128, nt * 128, As, Bs, acc);

    const int bb = m0 / S_, s0 = m0 % S_, h = n0 / HD;
    if (mat < 2) {
        u16* O = (mat == 0) ? Qo : Ko;
        const float qs = (mat == 0) ? 0.18033688011112042f : 1.0f;  // (1/8)*log2(e)
        #pragma unroll
        for (int jj = 0; jj < 4; ++jj) {
            float bv = bias[n0 + jj * 16 + lr];
            #pragma unroll
            for (int i = 0; i < 4; ++i)
                #pragma unroll
                for (int r = 0; r < 4; ++r) {
                    int s = s0 + i * 16 + quad * 4 + r;
                    O[((size_t)(bb * NH + h) * S_ + s) * HD + jj * 16 + lr] = f2bf((acc[i][jj][r] + bv) * qs);
                }
        }
    } else {
        #pragma unroll
        for (int jj = 0; jj < 4; ++jj) {
            float bv = bias[n0 + jj * 16 + lr];
            #pragma unroll
            for (int i = 0; i < 4; ++i) {
                int s = s0 + i * 16 + quad * 4;
                s16x4 o;
                o.x = (short)f2bf(acc[i][jj][0] + bv);
                o.y = (short)f2bf(acc[i][jj][1] + bv);
                o.z = (short)f2bf(acc[i][jj][2] + bv);
                o.w = (short)f2bf(acc[i][jj][3] + bv);
                *(s16x4*)(VTo + ((size_t)(bb * NH + h) * HD + jj * 16 + lr) * S_ + s) = o;
            }
        }
    }
}

// ---------------- flash attention (causal, NO-max softmax) ----------------
// R8 structure unchanged. R11: blockIdx->(bh,qc) BALANCED PERMUTATION only.
// Dispatch model (m09 + linear round-robin): CU j of an XCD receives i2 = j, j+32, j+64.
// Old map qc=15-i2/6 gave per-CU tile totals 36..66 (runtime set by 66). New closed-form
// triple design: column j gets qc {t, (t+8)&15, 22+e-s} (t=j>>1, e=j&1, s = sum of
// first two) -> per-CU totals exactly 50 or 52 tiles. Bijective over (bh_lo, qc):
// r=0/1 occurrences distinguished by e, r=2 by t>>3 (verified per-case).
// Pure index math: zero instruction-stream / register-pressure change.
__global__ __launch_bounds__(256, 3) void attn_kernel(
    const u16* __restrict__ Q, const u16* __restrict__ K,
    const u16* __restrict__ VT, u16* __restrict__ CTX)
{
    const int tid = threadIdx.x;
    const int wave = tid >> 6;
    const int lane = tid & 63;
    const int lr = lane & 15, quad = lane >> 4;

    const int xcd = blockIdx.x & 7;
    const int i2  = blockIdx.x >> 3;            // 0..95
    const int rr  = i2 >> 5;                    // per-CU slot 0..2
    const int jj  = i2 & 31;                    // CU within XCD (model)
    const int t   = jj >> 1, e = jj & 1;
    int qc, blo;
    if (rr == 0)      { qc = t;                                   blo = e; }
    else if (rr == 1) { qc = (t + 8) & 15;                        blo = 2 + e; }
    else              { qc = 22 + e - (t + ((t + 8) & 15));       blo = 4 + (t >> 3); }
    const int bh  = xcd * 6 + blo;
    const int Q0  = qc * 128;
    const int q0w = Q0 + wave * 32;             // this wave's 32 q-rows

    const u16* Qb = Q  + (size_t)bh * S_ * HD;
    const u16* Kb = K  + (size_t)bh * S_ * HD;
    const u16* Vb = VT + (size_t)bh * HD * S_;

    // double-buffered K/V tiles: 64 rows x 64 elems bf16 each = 8KB; total 32KB
    __shared__ __align__(16) u16 kbuf[2][64 * 64];
    __shared__ __align__(16) u16 vbuf[2][64 * 64];

    bf16x8 aq[2][2];
    #pragma unroll
    for (int mi = 0; mi < 2; ++mi)
        #pragma unroll
        for (int kk = 0; kk < 2; ++kk)
            aq[mi][kk] = *(const bf16x8*)(Qb + (size_t)(q0w + mi * 16 + lr) * HD + kk * 32 + quad * 8);

    f32x4 o[2][4] = {};
    f32x4 lacc[2] = {};
    bf16x8 ones;
    #pragma unroll
    for (int j = 0; j < 8; ++j) ones[j] = (short)0x3F80;   // bf16 1.0

    const int KT  = 2 * qc + 1;                 // block-uniform last tile
    const int ktw = (q0w + 31) >> 6;            // this wave's last tile

#define STAGE_KV(b, kk0) do {                                                   \
        _Pragma("unroll")                                                       \
        for (int j = 0; j < 2; ++j) {                                           \
            int ch  = ((j * 4 + wave) << 6) + lane;                             \
            int row = ch >> 3;                                                  \
            int cl  = (ch & 7) ^ (row & 7);                                     \
            GLD_LDS(Kb + (size_t)((kk0) + row) * HD + cl * 8, &kbuf[b][ch * 8]);\
            GLD_LDS(Vb + (size_t)row * S_ + (kk0) + cl * 8, &vbuf[b][ch * 8]);  \
        }                                                                       \
    } while (0)

    STAGE_KV(0, 0);
    __syncthreads();

    for (int kt = 0; kt <= KT; ++kt) {
        const int cur = kt & 1;
        if (kt < KT) STAGE_KV(cur ^ 1, (kt + 1) << 6);   // prefetch next tile

        if (kt <= ktw) {                                  // wave-uniform guard
            const int k0 = kt << 6;

            // K fragments from LDS (swizzled read)
            bf16x8 bk[4][2];
            #pragma unroll
            for (int t2 = 0; t2 < 4; ++t2)
                #pragma unroll
                for (int kk = 0; kk < 2; ++kk) {
                    int row = t2 * 16 + lr;
                    int cp  = (kk * 4 + quad) ^ (row & 7);
                    bk[t2][kk] = *(const bf16x8*)(&kbuf[cur][row * 64 + cp * 8]);
                }

            // swapped QK^T: lane holds q=lr, key=16t+quad*4+r
            f32x4 sT[2][4];
            #pragma unroll
            for (int mi = 0; mi < 2; ++mi)
                #pragma unroll
                for (int t2 = 0; t2 < 4; ++t2) {
                    f32x4 z = {0.f, 0.f, 0.f, 0.f};
                    z = __builtin_amdgcn_mfma_f32_16x16x32_bf16(bk[t2][0], aq[mi][0], z, 0, 0, 0);
                    z = __builtin_amdgcn_mfma_f32_16x16x32_bf16(bk[t2][1], aq[mi][1], z, 0, 0, 0);
                    sT[mi][t2] = z;
                }

            if (kt == ktw) {   // diagonal tile: causal mask (exp2(-inf) = 0)
                #pragma unroll
                for (int mi = 0; mi < 2; ++mi) {
                    int qrow = q0w + mi * 16 + lr;
                    #pragma unroll
                    for (int t2 = 0; t2 < 4; ++t2)
                        #pragma unroll
                        for (int r = 0; r < 4; ++r) {
                            int key = k0 + t2 * 16 + quad * 4 + r;
                            if (key > qrow) sT[mi][t2][r] = -INFINITY;
                        }
                }
            }

            // V fragments from LDS (swizzled read)
            bf16x8 bv[4][2];
            #pragma unroll
            for (int nv = 0; nv < 4; ++nv)
                #pragma unroll
                for (int c2 = 0; c2 < 2; ++c2) {
                    int row = nv * 16 + lr;
                    int cp  = (c2 * 4 + quad) ^ (row & 7);
                    bv[nv][c2] = *(const bf16x8*)(&vbuf[cur][row * 64 + cp * 8]);
                }

            // exp (Q pre-scaled by scale*log2e) + in-register transpose to A-layout
            bf16x8 pa[2][2];
            #pragma unroll
            for (int mi = 0; mi < 2; ++mi) {
                #pragma unroll
                for (int t2 = 0; t2 < 4; ++t2)
                    #pragma unroll
                    for (int r = 0; r < 4; ++r)
                        sT[mi][t2][r] = exp2f(sT[mi][t2][r]);

                #pragma unroll
                for (int c = 0; c < 2; ++c) {
                    unsigned u00 = pk2(sT[mi][2 * c + 0][0], sT[mi][2 * c + 0][1]);
                    unsigned u01 = pk2(sT[mi][2 * c + 0][2], sT[mi][2 * c + 0][3]);
                    unsigned u10 = pk2(sT[mi][2 * c + 1][0], sT[mi][2 * c + 1][1]);
                    unsigned u11 = pk2(sT[mi][2 * c + 1][2], sT[mi][2 * c + 1][3]);
                    swap32(u00, u10); swap16(u00, u10);
                    swap32(u01, u11); swap16(u01, u11);
                    u32x4 P = {u00, u01, u10, u11};
                    pa[mi][c] = __builtin_bit_cast(bf16x8, P);
                }
            }

            #pragma unroll
            for (int mi = 0; mi < 2; ++mi) {
                lacc[mi] = __builtin_amdgcn_mfma_f32_16x16x32_bf16(pa[mi][0], ones, lacc[mi], 0, 0, 0);
                lacc[mi] = __builtin_amdgcn_mfma_f32_16x16x32_bf16(pa[mi][1], ones, lacc[mi], 0, 0, 0);
                #pragma unroll
                for (int nv = 0; nv < 4; ++nv) {
                    o[mi][nv] = __builtin_amdgcn_mfma_f32_16x16x32_bf16(pa[mi][0], bv[nv][0], o[mi][nv], 0, 0, 0);
                    o[mi][nv] = __builtin_amdgcn_mfma_f32_16x16x32_bf16(pa[mi][1], bv[nv][1], o[mi][nv], 0, 0, 0);
                }
            }
        }

        __syncthreads();   // staging of kt+1 done; reads of buf[cur] done
    }
#undef STAGE_KV

    // -------- per-wave epilogue (no cross-wave reduction) --------
    const int bb = bh / NH, h = bh % NH;
    #pragma unroll
    for (int mi = 0; mi < 2; ++mi) {
        f32x4 inv;
        #pragma unroll
        for (int r = 0; r < 4; ++r) inv[r] = 1.0f / lacc[mi][r];
        #pragma unroll
        for (int nv = 0; nv < 4; ++nv)
            #pragma unroll
            for (int r = 0; r < 4; ++r)
                CTX[(size_t)(bb * S_ + q0w + mi * 16 + quad * 4 + r) * DM + h * HD + nv * 16 + lr]
                    = f2bf(o[mi][nv][r] * inv[r]);
    }
}

// ---------------- output projection GEMM (LDS-staged, fp32 out) ----------------
// R6 (T1): XCD-aware bijective remap. 384 = 8 XCD x 8 mt x 6 nt.
__global__ __launch_bounds__(256) void o_gemm(
    const u16* __restrict__ X, const u16* __restrict__ W,
    const float* __restrict__ bias, float* __restrict__ Out)
{
    __shared__ __align__(16) u16 As[128 * 32];
    __shared__ __align__(16) u16 Bs[128 * 32];

    const int xcd  = blockIdx.x & 7;
    const int slot = blockIdx.x >> 3;           // 0..47
    const int nt   = slot % 6;
    const int mt   = xcd * 8 + slot / 6;        // 0..63
    const int lane = threadIdx.x & 63;
    const int lr = lane & 15, quad = lane >> 4;
    const int wave = threadIdx.x >> 6;
    const int m0 = mt * 128 + (wave & 1) * 64;
    const int n0 = nt * 128 + (wave >> 1) * 64;

    f32x4 acc[4][4] = {};
    gemm_core_128(X, W, mt * 128, nt * 128, As, Bs, acc);

    #pragma unroll
    for (int jj = 0; jj < 4; ++jj) {
        float bv = bias[n0 + jj * 16 + lr];
        #pragma unroll
        for (int i = 0; i < 4; ++i)
            #pragma unroll
            for (int r = 0; r < 4; ++r)
                Out[(size_t)(m0 + i * 16 + quad * 4 + r) * DM + n0 + jj * 16 + lr] = acc[i][jj][r] + bv;
    }
}

extern "C" void kernel_launch(void* const* d_in, const int* in_sizes, int n_in,
                              void* d_out, int out_size, void* d_ws, size_t ws_size,
                              hipStream_t stream) {
    const float* q  = (const float*)d_in[0];
    const float* k  = (const float*)d_in[1];
    const float* v  = (const float*)d_in[2];
    const float* WQ = (const float*)d_in[3];
    const float* bQ = (const float*)d_in[4];
    const float* WK = (const float*)d_in[5];
    const float* bK = (const float*)d_in[6];
    const float* WV = (const float*)d_in[7];
    const float* bV = (const float*)d_in[8];
    const float* WO = (const float*)d_in[9];
    const float* bO = (const float*)d_in[10];

    char* ws = (char*)d_ws;
    const size_t SZ_X = (size_t)MT * DM * 2;   // 12,582,912 B
    const size_t SZ_W = (size_t)DM * DM * 2;   //  1,179,648 B
    u16* Xq = (u16*)(ws);
    u16* Xk = (u16*)(ws + SZ_X);
    u16* Xv = (u16*)(ws + 2 * SZ_X);
    u16* Wq = (u16*)(ws + 3 * SZ_X);
    u16* Wk = (u16*)(ws + 3 * SZ_X + SZ_W);
    u16* Wv = (u16*)(ws + 3 * SZ_X + 2 * SZ_W);
    u16* Wo = (u16*)(ws + 3 * SZ_X + 3 * SZ_W);
    u16* Qh  = (u16*)(ws + 3 * SZ_X + 4 * SZ_W);
    u16* Kh  = (u16*)(ws + 4 * SZ_X + 4 * SZ_W);
    u16* VTh = (u16*)(ws + 5 * SZ_X + 4 * SZ_W);
    u16* CTX = Xq;   // Xq dead after qkv_gemm; reuse

    const int nX = MT * DM;    // 6,291,456
    const int nW = DM * DM;    //   589,824
    const int xB = nX / 1024;  // 6144
    const int wB = nW / 1024;  //  576
    cvt_all<<<3 * xB + 4 * wB, 256, 0, stream>>>(q, k, v, WQ, WK, WV, WO,
                                                 Xq, Xk, Xv, Wq, Wk, Wv, Wo, xB, wB);

    qkv_gemm<<<1152, 256, 0, stream>>>(Xq, Xk, Xv, Wq, Wk, Wv, bQ, bK, bV, Qh, Kh, VTh);
    attn_kernel<<<768, 256, 0, stream>>>(Qh, Kh, VTh, CTX);
    o_gemm<<<384, 256, 0, stream>>>(CTX, Wo, bO, (float*)d_out);
}